// Round 7
// baseline (1171.494 us; speedup 1.0000x reference)
//
#include <hip/hip_runtime.h>
#include <math.h>

#define N_NODES 50000
#define N_EDGES 800000
#define D 128          // NODE_DIM
#define DE 10          // EDGE_DIM
#define K_TOT 266      // 2*D + DE
#define TE 64          // edges per tile (CSR-consecutive)
#define N_TILES (N_EDGES / TE)       // 12500
#define ZS1 136        // phase-1 LDS row stride (128 + 8 pad; 272B rows, 16B-aligned)
#define ZS2 168        // phase-2 LDS row stride (160 + 8 pad; 336B rows, 16B-aligned)
#define MS 130         // bf16 per m row in LDS epilogue buffer
#define SMEM_BYTES (TE * ZS2 * 2)    // 21504 B (max of phases; ms 16640 B fits)
#define WP_ELEMS (9 * 16 * 64 * 8)   // packed weight elements (bf16) = 73728
#define SCAN_BLOCKS 196              // 196*256 = 50176 >= 50000

typedef __bf16 bf16x8 __attribute__((ext_vector_type(8)));
typedef __bf16 bf16x4 __attribute__((ext_vector_type(4)));
typedef __bf16 bf16x2 __attribute__((ext_vector_type(2)));
typedef float  f32x4  __attribute__((ext_vector_type(4)));

// Single-HW-instruction transcendentals (v_exp_f32 / v_log_f32 / v_rcp_f32).
__device__ __forceinline__ float fast_sigmoid(float x) {
    float t = __builtin_amdgcn_exp2f(-1.44269504089f * x);
    return __builtin_amdgcn_rcpf(1.0f + t);
}
__device__ __forceinline__ float fast_softplus(float x) {
    float t = __builtin_amdgcn_exp2f(-1.44269504089f * fabsf(x));
    return fmaxf(x, 0.0f) + 0.69314718056f * __builtin_amdgcn_logf(1.0f + t);
}

// ---- fused prep: cvt h->bf16 | pack weights | CSR histogram ----
// counts/stats/agg pre-zeroed by one hipMemsetAsync (stream-ordered before us).
// [0,6250) cvt_h; [6250,6538) pack_weights; [6538,9663) hist.
__global__ __launch_bounds__(256) void prep(
    const float* __restrict__ h, const float* __restrict__ gw,
    const float* __restrict__ cw, const int* __restrict__ ei,
    __bf16* __restrict__ hb, __bf16* __restrict__ wp,
    int* __restrict__ counts)
{
    int bx = blockIdx.x, t = threadIdx.x;
    if (bx < 6250) {
        int i4 = bx * 256 + t;
        float4 v = *(const float4*)&h[(size_t)i4 * 4];
        bf16x4 o = { (__bf16)v.x, (__bf16)v.y, (__bf16)v.z, (__bf16)v.w };
        *(bf16x4*)&hb[(size_t)i4 * 4] = o;
    } else if (bx < 6538) {
        int idx = (bx - 6250) * 256 + t;
        if (idx < WP_ELEMS) {
            int j    = idx & 7;
            int lane = (idx >> 3) & 63;
            int nb   = (idx >> 9) & 15;
            int kb   = idx >> 13;
            int k    = kb * 32 + ((lane >> 4) << 3) + j;
            int col  = ((nb >> 1) << 4) + (lane & 15);
            const float* w = (nb & 1) ? cw : gw;
            float v = (k < K_TOT) ? w[k * D + col] : 0.0f;
            wp[idx] = (__bf16)v;
        }
    } else {
        int e = (bx - 6538) * 256 + t;      // exact: 3125*256 = 800000
        atomicAdd(&counts[ei[e]], 1);
    }
}

// Phase 1: per-block sums of 256 counts
__global__ __launch_bounds__(256) void scan_partials(
    const int* __restrict__ counts, int* __restrict__ bsum)
{
    __shared__ int ss[256];
    int t = threadIdx.x;
    int i = blockIdx.x * 256 + t;
    int c = (i < N_NODES) ? counts[i] : 0;
    ss[t] = c;
    __syncthreads();
    #pragma unroll
    for (int off = 1; off < 256; off <<= 1) {
        int v = (t >= off) ? ss[t - off] : 0;
        __syncthreads();
        ss[t] += v;
        __syncthreads();
    }
    if (t == 255) bsum[blockIdx.x] = ss[255];
}

// Phase 2: each block re-scans the 196 partials for its base, then block-local
// exclusive scan of counts -> cursor.
__global__ __launch_bounds__(256) void scan_final(
    const int* __restrict__ counts, const int* __restrict__ bsum,
    int* __restrict__ cursor)
{
    __shared__ int sb[256];
    __shared__ int ss[256];
    int t = threadIdx.x;
    sb[t] = (t < SCAN_BLOCKS) ? bsum[t] : 0;
    int i = blockIdx.x * 256 + t;
    int c = (i < N_NODES) ? counts[i] : 0;
    ss[t] = c;
    __syncthreads();
    #pragma unroll
    for (int off = 1; off < 256; off <<= 1) {
        int v  = (t >= off) ? ss[t - off] : 0;
        int vb = (t >= off) ? sb[t - off] : 0;
        __syncthreads();
        ss[t] += v;
        sb[t] += vb;
        __syncthreads();
    }
    int base = blockIdx.x ? sb[blockIdx.x - 1] : 0;
    if (i < N_NODES) cursor[i] = base + ss[t] - c;
}

__global__ __launch_bounds__(256) void csr_scatter(
    const int* __restrict__ ei, int* __restrict__ cursor,
    int* __restrict__ eidx)
{
    int e = blockIdx.x * 256 + threadIdx.x;   // grid exact: 800000
    int pos = atomicAdd(&cursor[ei[e]], 1);
    eidx[pos] = e;
}

// ---- main: per CSR-ordered 64-edge tile, TWO-PHASE K (halved LDS ->
// 6 blocks/CU residency vs R5's 3.5). Phase 1: z-rows = h[src] (k 0..127).
// Phase 2: z-rows = h[dst] + ef + pad (k 128..287). acc carries across.
// Epilogue: m (bf16) -> LDS, run-segmented reduction, one atomic per
// distinct (node,col) per tile. ----
__global__ __launch_bounds__(256, 6) void edge_mfma_scatter(
    const __bf16* __restrict__ hb, const int* __restrict__ ei,
    const float* __restrict__ ef, const __bf16* __restrict__ wp,
    const float* __restrict__ gb, const float* __restrict__ cb,
    const int* __restrict__ eidx, float* __restrict__ agg)
{
    __shared__ __align__(16) unsigned char smem[SMEM_BYTES];   // 21504 B
    __shared__ int s_eid[TE], s_src[TE], s_dst[TE];
    __bf16* zs  = (__bf16*)smem;
    __bf16* msb = (__bf16*)smem;      // reused after phase-2 K-loop

    const int t     = threadIdx.x;
    const int w     = t >> 6;
    const int l     = t & 63;
    const int quad  = l >> 4;
    const int col16 = l & 15;
    const int e0    = blockIdx.x * TE;

    if (t < TE) {
        int eid = eidx[e0 + t];
        s_eid[t] = eid;
        s_src[t] = ei[eid];
        s_dst[t] = ei[N_EDGES + eid];
    }
    __syncthreads();

    f32x4 acc[4][4];
    #pragma unroll
    for (int mt = 0; mt < 4; ++mt)
        #pragma unroll
        for (int nt = 0; nt < 4; ++nt)
            acc[mt][nt] = (f32x4)0.0f;

    const __bf16* wpp = &wp[(size_t)((w * 4) * 64 + l) * 8];

    // ======== phase 1: k = 0..127 (h[src]) ========
    #pragma unroll
    for (int it = 0; it < 4; ++it) {
        int lin = it * 256 + t;            // 1024 bf16x8 slots
        int r   = lin >> 4;
        int seg = lin & 15;
        bf16x8 v = *(const bf16x8*)&hb[(size_t)s_src[r] * D + seg * 8];
        *(bf16x8*)&zs[r * ZS1 + seg * 8] = v;
    }
    __syncthreads();

    {
        const __bf16* zp = &zs[col16 * ZS1 + quad * 8];
        #pragma unroll
        for (int kb = 0; kb < 4; ++kb) {
            bf16x8 afr[4];
            #pragma unroll
            for (int mt = 0; mt < 4; ++mt)
                afr[mt] = *(const bf16x8*)&zp[mt * 16 * ZS1 + kb * 32];
            bf16x8 bfr[4];
            #pragma unroll
            for (int nt = 0; nt < 4; ++nt)
                bfr[nt] = *(const bf16x8*)&wpp[(size_t)(kb * 16 + nt) * 512];
            #pragma unroll
            for (int mt = 0; mt < 4; ++mt)
                #pragma unroll
                for (int nt = 0; nt < 4; ++nt)
                    acc[mt][nt] = __builtin_amdgcn_mfma_f32_16x16x32_bf16(
                        afr[mt], bfr[nt], acc[mt][nt], 0, 0, 0);
        }
    }
    __syncthreads();   // phase-1 zs reads done

    // ======== phase 2: k = 128..287 (h[dst] | ef | pad) ========
    #pragma unroll
    for (int it = 0; it < 4; ++it) {
        int lin = it * 256 + t;
        int r   = lin >> 4;
        int seg = lin & 15;
        bf16x8 v = *(const bf16x8*)&hb[(size_t)s_dst[r] * D + seg * 8];
        *(bf16x8*)&zs[r * ZS2 + seg * 8] = v;
    }
    if (t < TE) {
        const float* efr = &ef[(size_t)s_eid[t] * DE];   // 40B rows, 8B-aligned
        __bf16* row = &zs[t * ZS2 + 128];
        #pragma unroll
        for (int j = 0; j < 5; ++j) {
            float2 a = *(const float2*)&efr[j * 2];
            bf16x2 p = { (__bf16)a.x, (__bf16)a.y };
            *(bf16x2*)&row[j * 2] = p;
        }
        *(bf16x2*)&row[10] = (bf16x2)(__bf16)0.0f;
        *(bf16x4*)&row[12] = (bf16x4)(__bf16)0.0f;
        *(bf16x8*)&row[16] = (bf16x8)(__bf16)0.0f;
        *(bf16x8*)&row[24] = (bf16x8)(__bf16)0.0f;
    }
    __syncthreads();

    {
        const __bf16* zp = &zs[col16 * ZS2 + quad * 8];
        #pragma unroll
        for (int kb = 0; kb < 5; ++kb) {
            bf16x8 afr[4];
            #pragma unroll
            for (int mt = 0; mt < 4; ++mt)
                afr[mt] = *(const bf16x8*)&zp[mt * 16 * ZS2 + kb * 32];
            bf16x8 bfr[4];
            #pragma unroll
            for (int nt = 0; nt < 4; ++nt)
                bfr[nt] = *(const bf16x8*)&wpp[(size_t)((kb + 4) * 16 + nt) * 512];
            #pragma unroll
            for (int mt = 0; mt < 4; ++mt)
                #pragma unroll
                for (int nt = 0; nt < 4; ++nt)
                    acc[mt][nt] = __builtin_amdgcn_mfma_f32_16x16x32_bf16(
                        afr[mt], bfr[nt], acc[mt][nt], 0, 0, 0);
        }
    }
    __syncthreads();   // phase-2 zs reads done; smem becomes msb

    // ---- m = sigmoid(g+gb)*softplus(c+cb) -> LDS (bf16) ----
    const int colA = w * 32 + col16;
    const int colB = colA + 16;
    const float gbA = gb[colA], cbA = cb[colA];
    const float gbB = gb[colB], cbB = cb[colB];

    #pragma unroll
    for (int mt = 0; mt < 4; ++mt) {
        #pragma unroll
        for (int r = 0; r < 4; ++r) {
            int e = mt * 16 + quad * 4 + r;
            float m0 = fast_sigmoid(acc[mt][0][r] + gbA) * fast_softplus(acc[mt][1][r] + cbA);
            float m1 = fast_sigmoid(acc[mt][2][r] + gbB) * fast_softplus(acc[mt][3][r] + cbB);
            msb[e * MS + colA] = (__bf16)m0;
            msb[e * MS + colB] = (__bf16)m1;
        }
    }
    __syncthreads();

    // ---- run-segmented reduction, one atomic per run ----
    {
        const int half = t >> 7;           // rows [half*32, half*32+32)
        const int c    = t & 127;
        const int rlo  = half * 32, rhi = rlo + 32;
        int   cur = s_src[rlo];
        float s   = 0.0f;
        for (int e = rlo; e < rhi; ++e) {
            int node = s_src[e];
            float v  = (float)msb[e * MS + c];
            if (node != cur) {
                atomicAdd(&agg[(size_t)cur * D + c], s);
                s = 0.0f; cur = node;
            }
            s += v;
        }
        atomicAdd(&agg[(size_t)cur * D + c], s);
    }
}

__global__ __launch_bounds__(256) void col_stats(
    const float* __restrict__ agg, float* __restrict__ stats)
{
    const int t    = threadIdx.x;
    const int col  = t & 127;
    const int half = t >> 7;
    float s = 0.0f, s2 = 0.0f;
    for (int r = blockIdx.x * 2 + half; r < N_NODES; r += gridDim.x * 2) {
        float v = agg[(size_t)r * D + col];
        s += v; s2 += v * v;
    }
    atomicAdd(&stats[col], s);
    atomicAdd(&stats[128 + col], s2);
}

// BN finalize folded in: each block recomputes scale/bias from L2-hot stats.
__global__ __launch_bounds__(256) void out_softplus(
    const float* __restrict__ h, const float* __restrict__ agg,
    const float* __restrict__ stats, const float* __restrict__ gamma,
    const float* __restrict__ beta, float* __restrict__ out)
{
    __shared__ float sc[128], bi[128];
    int t = threadIdx.x;
    if (t < 128) {
        const float inv_n = 1.0f / (float)N_NODES;
        float mean = stats[t] * inv_n;
        float var  = stats[128 + t] * inv_n - mean * mean;
        var = fmaxf(var, 0.0f);
        float rstd = rsqrtf(var + 1e-5f);
        float s = rstd * gamma[t];
        sc[t] = s;
        bi[t] = beta[t] - mean * s;
    }
    __syncthreads();
    int idx4 = blockIdx.x * 256 + t;
    int base = idx4 * 4;
    if (base < N_NODES * D) {
        float4 hv = *(const float4*)&h[base];
        float4 av = *(const float4*)&agg[base];
        int c = base & 127;
        float4 o;
        o.x = fast_softplus(hv.x + av.x * sc[c + 0] + bi[c + 0]);
        o.y = fast_softplus(hv.y + av.y * sc[c + 1] + bi[c + 1]);
        o.z = fast_softplus(hv.z + av.z * sc[c + 2] + bi[c + 2]);
        o.w = fast_softplus(hv.w + av.w * sc[c + 3] + bi[c + 3]);
        *(float4*)&out[base] = o;
    }
}

extern "C" void kernel_launch(void* const* d_in, const int* in_sizes, int n_in,
                              void* d_out, int out_size, void* d_ws, size_t ws_size,
                              hipStream_t stream) {
    const float* h     = (const float*)d_in[0];
    const int*   ei    = (const int*)  d_in[1];
    const float* ef    = (const float*)d_in[2];
    const float* gw    = (const float*)d_in[3];
    const float* gb    = (const float*)d_in[4];
    const float* cw    = (const float*)d_in[5];
    const float* cb    = (const float*)d_in[6];
    const float* gamma = (const float*)d_in[7];
    const float* beta  = (const float*)d_in[8];
    float* out = (float*)d_out;

    // zeroed region first (one memset): agg | stats | counts
    float*  agg     = (float*)d_ws;                       // 25.6 MB
    float*  stats   = agg + (size_t)N_NODES * D;          // 256 f
    int*    counts  = (int*)(stats + 256);                // 200 KB
    int*    cursor  = counts + N_NODES;                   // 200 KB
    int*    bsum    = cursor + N_NODES;                   // 256 ints
    __bf16* wp      = (__bf16*)(bsum + 256);              // 144 KB (16B-aligned)
    __bf16* hb      = wp + WP_ELEMS;                      // 12.8 MB (16B-aligned)
    int*    eidx    = (int*)(hb + (size_t)N_NODES * D);   // 3.2 MB
    // total ~42.2 MB

    const size_t zero_bytes = ((size_t)N_NODES * D + 256) * sizeof(float)
                            + (size_t)N_NODES * sizeof(int);
    hipMemsetAsync(d_ws, 0, zero_bytes, stream);
    prep<<<9663, 256, 0, stream>>>(h, gw, cw, ei, hb, wp, counts);
    scan_partials<<<SCAN_BLOCKS, 256, 0, stream>>>(counts, bsum);
    scan_final<<<SCAN_BLOCKS, 256, 0, stream>>>(counts, bsum, cursor);
    csr_scatter<<<N_EDGES / 256, 256, 0, stream>>>(ei, cursor, eidx);
    edge_mfma_scatter<<<N_TILES, 256, 0, stream>>>(hb, ei, ef, wp, gb, cb, eidx, agg);
    col_stats<<<200, 256, 0, stream>>>(agg, stats);
    out_softplus<<<(N_NODES * D / 4 + 255) / 256, 256, 0, stream>>>(
        h, agg, stats, gamma, beta, out);
}

// Round 8
// 417.286 us; speedup vs baseline: 2.8074x; 2.8074x over previous
//
#include <hip/hip_runtime.h>
#include <math.h>

#define N_NODES 50000
#define N_EDGES 800000
#define D 128          // NODE_DIM
#define DE 10          // EDGE_DIM
#define K_TOT 266      // 2*D + DE
#define TE 64          // edges per tile (CSR-consecutive)
#define N_TILES (N_EDGES / TE)       // 12500
#define ZSTRIDE 296    // bf16 per z row in LDS (288 + 8 pad; 2-way bank alias = free)
#define MSTRIDE 129    // f32 per m row in LDS epilogue buffer
#define WP_ELEMS (9 * 16 * 64 * 8)   // packed weight elements (bf16) = 73728
#define SCAN_BLOCKS 196              // 196*256 = 50176 >= 50000

typedef __bf16 bf16x8 __attribute__((ext_vector_type(8)));
typedef __bf16 bf16x4 __attribute__((ext_vector_type(4)));
typedef __bf16 bf16x2 __attribute__((ext_vector_type(2)));
typedef float  f32x4  __attribute__((ext_vector_type(4)));

// Single-HW-instruction transcendentals (v_exp_f32 / v_log_f32 / v_rcp_f32).
__device__ __forceinline__ float fast_sigmoid(float x) {
    float t = __builtin_amdgcn_exp2f(-1.44269504089f * x);
    return __builtin_amdgcn_rcpf(1.0f + t);
}
__device__ __forceinline__ float fast_softplus(float x) {
    float t = __builtin_amdgcn_exp2f(-1.44269504089f * fabsf(x));
    return fmaxf(x, 0.0f) + 0.69314718056f * __builtin_amdgcn_logf(1.0f + t);
}

// ---- fused prep: cvt h->bf16 | pack weights | CSR histogram ----
// counts/stats/agg pre-zeroed by one hipMemsetAsync (stream-ordered before us).
// [0,6250) cvt_h; [6250,6538) pack_weights; [6538,9663) hist.
__global__ __launch_bounds__(256) void prep(
    const float* __restrict__ h, const float* __restrict__ gw,
    const float* __restrict__ cw, const int* __restrict__ ei,
    __bf16* __restrict__ hb, __bf16* __restrict__ wp,
    int* __restrict__ counts)
{
    int bx = blockIdx.x, t = threadIdx.x;
    if (bx < 6250) {
        int i4 = bx * 256 + t;
        float4 v = *(const float4*)&h[(size_t)i4 * 4];
        bf16x4 o = { (__bf16)v.x, (__bf16)v.y, (__bf16)v.z, (__bf16)v.w };
        *(bf16x4*)&hb[(size_t)i4 * 4] = o;
    } else if (bx < 6538) {
        int idx = (bx - 6250) * 256 + t;
        if (idx < WP_ELEMS) {
            int j    = idx & 7;
            int lane = (idx >> 3) & 63;
            int nb   = (idx >> 9) & 15;
            int kb   = idx >> 13;
            int k    = kb * 32 + ((lane >> 4) << 3) + j;
            int col  = ((nb >> 1) << 4) + (lane & 15);
            const float* w = (nb & 1) ? cw : gw;
            float v = (k < K_TOT) ? w[k * D + col] : 0.0f;
            wp[idx] = (__bf16)v;
        }
    } else {
        int e = (bx - 6538) * 256 + t;      // exact: 3125*256 = 800000
        atomicAdd(&counts[ei[e]], 1);
    }
}

// Phase 1: per-block sums of 256 counts
__global__ __launch_bounds__(256) void scan_partials(
    const int* __restrict__ counts, int* __restrict__ bsum)
{
    __shared__ int ss[256];
    int t = threadIdx.x;
    int i = blockIdx.x * 256 + t;
    int c = (i < N_NODES) ? counts[i] : 0;
    ss[t] = c;
    __syncthreads();
    #pragma unroll
    for (int off = 1; off < 256; off <<= 1) {
        int v = (t >= off) ? ss[t - off] : 0;
        __syncthreads();
        ss[t] += v;
        __syncthreads();
    }
    if (t == 255) bsum[blockIdx.x] = ss[255];
}

// Phase 2: each block re-scans the 196 partials for its base, then block-local
// exclusive scan of counts -> cursor.
__global__ __launch_bounds__(256) void scan_final(
    const int* __restrict__ counts, const int* __restrict__ bsum,
    int* __restrict__ cursor)
{
    __shared__ int sb[256];
    __shared__ int ss[256];
    int t = threadIdx.x;
    sb[t] = (t < SCAN_BLOCKS) ? bsum[t] : 0;
    int i = blockIdx.x * 256 + t;
    int c = (i < N_NODES) ? counts[i] : 0;
    ss[t] = c;
    __syncthreads();
    #pragma unroll
    for (int off = 1; off < 256; off <<= 1) {
        int v  = (t >= off) ? ss[t - off] : 0;
        int vb = (t >= off) ? sb[t - off] : 0;
        __syncthreads();
        ss[t] += v;
        sb[t] += vb;
        __syncthreads();
    }
    int base = blockIdx.x ? sb[blockIdx.x - 1] : 0;
    if (i < N_NODES) cursor[i] = base + ss[t] - c;
}

__global__ __launch_bounds__(256) void csr_scatter(
    const int* __restrict__ ei, int* __restrict__ cursor,
    int* __restrict__ eidx)
{
    int e = blockIdx.x * 256 + threadIdx.x;   // grid exact: 800000
    int pos = atomicAdd(&cursor[ei[e]], 1);
    eidx[pos] = e;
}

// ---- main (R5-proven structure): per CSR-ordered 64-edge tile: stage z,
// MFMA [64x288]@[288x256], fused act, run-segmented reduction, one atomic per
// distinct (node,col) per tile (~8M vs 102.4M naive).
// NOTE: __launch_bounds__(256,4) — do NOT raise the waves/EU bound: the 4x4
// f32x4 accumulator tile needs 64 regs; (256,6) forces spill (R7: 2.3x regress,
// FETCH 239MB->1.6GB scratch traffic). ----
__global__ __launch_bounds__(256, 4) void edge_mfma_scatter(
    const __bf16* __restrict__ hb, const int* __restrict__ ei,
    const float* __restrict__ ef, const __bf16* __restrict__ wp,
    const float* __restrict__ gb, const float* __restrict__ cb,
    const int* __restrict__ eidx, float* __restrict__ agg)
{
    __shared__ __align__(16) unsigned char smem[TE * ZSTRIDE * 2]; // 37,888 B
    __shared__ int s_eid[TE], s_src[TE], s_dst[TE];
    __bf16* zs = (__bf16*)smem;
    float*  ms = (float*)smem;       // reused after MFMA (64 x MSTRIDE f32)

    const int t  = threadIdx.x;
    const int e0 = blockIdx.x * TE;

    if (t < TE) {
        int eid = eidx[e0 + t];
        s_eid[t] = eid;
        s_src[t] = ei[eid];
        s_dst[t] = ei[N_EDGES + eid];
    }
    __syncthreads();

    // ---- stage z tile (bf16): h[src] rows k=0..127, h[dst] k=128..255 ----
    #pragma unroll
    for (int it = 0; it < 8; ++it) {
        int lin = it * 256 + t;
        int region = lin >> 10;            // 0 = src, 1 = dst
        int r   = (lin >> 4) & 63;
        int seg = lin & 15;
        int node = region ? s_dst[r] : s_src[r];
        bf16x8 v = *(const bf16x8*)&hb[(size_t)node * D + seg * 8];
        *(bf16x8*)&zs[r * ZSTRIDE + region * 128 + seg * 8] = v;
    }
    // k 256..287: edge_feat (float2 x5) + zero pad (22)
    if (t < TE) {
        const float* efr = &ef[(size_t)s_eid[t] * DE];   // 40B rows, 8B-aligned
        __bf16* row = &zs[t * ZSTRIDE + 256];
        #pragma unroll
        for (int j = 0; j < 5; ++j) {
            float2 a = *(const float2*)&efr[j * 2];
            bf16x2 p = { (__bf16)a.x, (__bf16)a.y };
            *(bf16x2*)&row[j * 2] = p;
        }
        *(bf16x2*)&row[10] = (bf16x2)(__bf16)0.0f;
        *(bf16x4*)&row[12] = (bf16x4)(__bf16)0.0f;
        *(bf16x8*)&row[16] = (bf16x8)(__bf16)0.0f;
        *(bf16x8*)&row[24] = (bf16x8)(__bf16)0.0f;
    }
    __syncthreads();

    // ---- MFMA: [64 x 288] @ [288 x 256] ----
    const int w     = t >> 6;
    const int l     = t & 63;
    const int quad  = l >> 4;
    const int col16 = l & 15;

    f32x4 acc[4][4];
    #pragma unroll
    for (int mt = 0; mt < 4; ++mt)
        #pragma unroll
        for (int nt = 0; nt < 4; ++nt)
            acc[mt][nt] = (f32x4)0.0f;

    const __bf16* zp  = &zs[col16 * ZSTRIDE + quad * 8];
    const __bf16* wpp = &wp[(size_t)((w * 4) * 64 + l) * 8];

    #pragma unroll
    for (int kb = 0; kb < 9; ++kb) {
        bf16x8 afr[4];
        #pragma unroll
        for (int mt = 0; mt < 4; ++mt)
            afr[mt] = *(const bf16x8*)&zp[mt * 16 * ZSTRIDE + kb * 32];
        bf16x8 bfr[4];
        #pragma unroll
        for (int nt = 0; nt < 4; ++nt)
            bfr[nt] = *(const bf16x8*)&wpp[(size_t)(kb * 16 + nt) * 512];
        #pragma unroll
        for (int mt = 0; mt < 4; ++mt)
            #pragma unroll
            for (int nt = 0; nt < 4; ++nt)
                acc[mt][nt] = __builtin_amdgcn_mfma_f32_16x16x32_bf16(
                    afr[mt], bfr[nt], acc[mt][nt], 0, 0, 0);
    }
    __syncthreads();   // all waves done reading zs; safe to overwrite as ms

    // ---- m = sigmoid(g+gb)*softplus(c+cb) -> LDS ----
    const int colA = w * 32 + col16;
    const int colB = colA + 16;
    const float gbA = gb[colA], cbA = cb[colA];
    const float gbB = gb[colB], cbB = cb[colB];

    #pragma unroll
    for (int mt = 0; mt < 4; ++mt) {
        #pragma unroll
        for (int r = 0; r < 4; ++r) {
            int e = mt * 16 + quad * 4 + r;
            ms[e * MSTRIDE + colA] =
                fast_sigmoid(acc[mt][0][r] + gbA) * fast_softplus(acc[mt][1][r] + cbA);
            ms[e * MSTRIDE + colB] =
                fast_sigmoid(acc[mt][2][r] + gbB) * fast_softplus(acc[mt][3][r] + cbB);
        }
    }
    __syncthreads();

    // ---- run-segmented reduction over CSR-sorted rows, one atomic per run ----
    const int half = t >> 7;           // rows [half*32, half*32+32)
    const int c    = t & 127;
    const int rlo  = half * 32, rhi = rlo + 32;
    int   cur = s_src[rlo];
    float s   = 0.0f;
    for (int e = rlo; e < rhi; ++e) {
        int node = s_src[e];
        float v  = ms[e * MSTRIDE + c];
        if (node != cur) {
            atomicAdd(&agg[(size_t)cur * D + c], s);
            s = 0.0f; cur = node;
        }
        s += v;
    }
    atomicAdd(&agg[(size_t)cur * D + c], s);
}

__global__ __launch_bounds__(256) void col_stats(
    const float* __restrict__ agg, float* __restrict__ stats)
{
    const int t    = threadIdx.x;
    const int col  = t & 127;
    const int half = t >> 7;
    float s = 0.0f, s2 = 0.0f;
    for (int r = blockIdx.x * 2 + half; r < N_NODES; r += gridDim.x * 2) {
        float v = agg[(size_t)r * D + col];
        s += v; s2 += v * v;
    }
    atomicAdd(&stats[col], s);
    atomicAdd(&stats[128 + col], s2);
}

// BN finalize folded in: each block recomputes scale/bias from L2-hot stats.
__global__ __launch_bounds__(256) void out_softplus(
    const float* __restrict__ h, const float* __restrict__ agg,
    const float* __restrict__ stats, const float* __restrict__ gamma,
    const float* __restrict__ beta, float* __restrict__ out)
{
    __shared__ float sc[128], bi[128];
    int t = threadIdx.x;
    if (t < 128) {
        const float inv_n = 1.0f / (float)N_NODES;
        float mean = stats[t] * inv_n;
        float var  = stats[128 + t] * inv_n - mean * mean;
        var = fmaxf(var, 0.0f);
        float rstd = rsqrtf(var + 1e-5f);
        float s = rstd * gamma[t];
        sc[t] = s;
        bi[t] = beta[t] - mean * s;
    }
    __syncthreads();
    int idx4 = blockIdx.x * 256 + t;
    int base = idx4 * 4;
    if (base < N_NODES * D) {
        float4 hv = *(const float4*)&h[base];
        float4 av = *(const float4*)&agg[base];
        int c = base & 127;
        float4 o;
        o.x = fast_softplus(hv.x + av.x * sc[c + 0] + bi[c + 0]);
        o.y = fast_softplus(hv.y + av.y * sc[c + 1] + bi[c + 1]);
        o.z = fast_softplus(hv.z + av.z * sc[c + 2] + bi[c + 2]);
        o.w = fast_softplus(hv.w + av.w * sc[c + 3] + bi[c + 3]);
        *(float4*)&out[base] = o;
    }
}

extern "C" void kernel_launch(void* const* d_in, const int* in_sizes, int n_in,
                              void* d_out, int out_size, void* d_ws, size_t ws_size,
                              hipStream_t stream) {
    const float* h     = (const float*)d_in[0];
    const int*   ei    = (const int*)  d_in[1];
    const float* ef    = (const float*)d_in[2];
    const float* gw    = (const float*)d_in[3];
    const float* gb    = (const float*)d_in[4];
    const float* cw    = (const float*)d_in[5];
    const float* cb    = (const float*)d_in[6];
    const float* gamma = (const float*)d_in[7];
    const float* beta  = (const float*)d_in[8];
    float* out = (float*)d_out;

    // zeroed region first (one memset): agg | stats | counts
    float*  agg     = (float*)d_ws;                       // 25.6 MB
    float*  stats   = agg + (size_t)N_NODES * D;          // 256 f
    int*    counts  = (int*)(stats + 256);                // 200 KB
    int*    cursor  = counts + N_NODES;                   // 200 KB
    int*    bsum    = cursor + N_NODES;                   // 256 ints
    __bf16* wp      = (__bf16*)(bsum + 256);              // 144 KB (16B-aligned)
    __bf16* hb      = wp + WP_ELEMS;                      // 12.8 MB (16B-aligned)
    int*    eidx    = (int*)(hb + (size_t)N_NODES * D);   // 3.2 MB
    // total ~42.2 MB

    const size_t zero_bytes = ((size_t)N_NODES * D + 256) * sizeof(float)
                            + (size_t)N_NODES * sizeof(int);
    hipMemsetAsync(d_ws, 0, zero_bytes, stream);
    prep<<<9663, 256, 0, stream>>>(h, gw, cw, ei, hb, wp, counts);
    scan_partials<<<SCAN_BLOCKS, 256, 0, stream>>>(counts, bsum);
    scan_final<<<SCAN_BLOCKS, 256, 0, stream>>>(counts, bsum, cursor);
    csr_scatter<<<N_EDGES / 256, 256, 0, stream>>>(ei, cursor, eidx);
    edge_mfma_scatter<<<N_TILES, 256, 0, stream>>>(hb, ei, ef, wp, gb, cb, eidx, agg);
    col_stats<<<200, 256, 0, stream>>>(agg, stats);
    out_softplus<<<(N_NODES * D / 4 + 255) / 256, 256, 0, stream>>>(
        h, agg, stats, gamma, beta, out);
}

// Round 9
// 414.234 us; speedup vs baseline: 2.8281x; 1.0074x over previous
//
#include <hip/hip_runtime.h>
#include <math.h>

#define N_NODES 50000
#define N_EDGES 800000
#define D 128          // NODE_DIM
#define DE 10          // EDGE_DIM
#define K_TOT 266      // 2*D + DE
#define TE 64          // edges per tile (CSR-consecutive)
#define N_TILES (N_EDGES / TE)       // 12500
#define ZSTRIDE 296    // bf16 per z row in LDS (288 + 8 pad; 2-way bank alias = free)
#define MSTRIDE 129    // f32 per m row in LDS epilogue buffer
#define WP_ELEMS (9 * 16 * 64 * 8)   // packed weight elements (bf16) = 73728
#define SCAN_BLOCKS 196              // 196*256 = 50176 >= 50000
#define CSTRIDE 16     // ints per histogram bin: one 64B line per node (kills
                       // TCC line-level atomic serialization; R8 theory)

typedef __bf16 bf16x8 __attribute__((ext_vector_type(8)));
typedef __bf16 bf16x4 __attribute__((ext_vector_type(4)));
typedef __bf16 bf16x2 __attribute__((ext_vector_type(2)));
typedef float  f32x4  __attribute__((ext_vector_type(4)));

// Single-HW-instruction transcendentals (v_exp_f32 / v_log_f32 / v_rcp_f32).
__device__ __forceinline__ float fast_sigmoid(float x) {
    float t = __builtin_amdgcn_exp2f(-1.44269504089f * x);
    return __builtin_amdgcn_rcpf(1.0f + t);
}
__device__ __forceinline__ float fast_softplus(float x) {
    float t = __builtin_amdgcn_exp2f(-1.44269504089f * fabsf(x));
    return fmaxf(x, 0.0f) + 0.69314718056f * __builtin_amdgcn_logf(1.0f + t);
}

// ---- fused prep: cvt h->bf16 | pack weights | CSR histogram ----
// counts/stats/agg pre-zeroed by one hipMemsetAsync.
// [0,6250) cvt_h; [6250,6538) pack_weights; [6538,9663) hist.
__global__ __launch_bounds__(256) void prep(
    const float* __restrict__ h, const float* __restrict__ gw,
    const float* __restrict__ cw, const int* __restrict__ ei,
    __bf16* __restrict__ hb, __bf16* __restrict__ wp,
    int* __restrict__ counts)
{
    int bx = blockIdx.x, t = threadIdx.x;
    if (bx < 6250) {
        int i4 = bx * 256 + t;
        float4 v = *(const float4*)&h[(size_t)i4 * 4];
        bf16x4 o = { (__bf16)v.x, (__bf16)v.y, (__bf16)v.z, (__bf16)v.w };
        *(bf16x4*)&hb[(size_t)i4 * 4] = o;
    } else if (bx < 6538) {
        int idx = (bx - 6250) * 256 + t;
        if (idx < WP_ELEMS) {
            int j    = idx & 7;
            int lane = (idx >> 3) & 63;
            int nb   = (idx >> 9) & 15;
            int kb   = idx >> 13;
            int k    = kb * 32 + ((lane >> 4) << 3) + j;
            int col  = ((nb >> 1) << 4) + (lane & 15);
            const float* w = (nb & 1) ? cw : gw;
            float v = (k < K_TOT) ? w[k * D + col] : 0.0f;
            wp[idx] = (__bf16)v;
        }
    } else {
        int e = (bx - 6538) * 256 + t;      // exact: 3125*256 = 800000
        atomicAdd(&counts[ei[e] * CSTRIDE], 1);
    }
}

// Phase 1: per-block sums of 256 (strided) counts
__global__ __launch_bounds__(256) void scan_partials(
    const int* __restrict__ counts, int* __restrict__ bsum)
{
    __shared__ int ss[256];
    int t = threadIdx.x;
    int i = blockIdx.x * 256 + t;
    int c = (i < N_NODES) ? counts[i * CSTRIDE] : 0;
    ss[t] = c;
    __syncthreads();
    #pragma unroll
    for (int off = 1; off < 256; off <<= 1) {
        int v = (t >= off) ? ss[t - off] : 0;
        __syncthreads();
        ss[t] += v;
        __syncthreads();
    }
    if (t == 255) bsum[blockIdx.x] = ss[255];
}

// Phase 2: block base from re-scan of partials + block-local exclusive scan.
// Writes the cursor IN PLACE over counts (counts dead afterwards).
__global__ __launch_bounds__(256) void scan_final(
    int* __restrict__ counts, const int* __restrict__ bsum)
{
    __shared__ int sb[256];
    __shared__ int ss[256];
    int t = threadIdx.x;
    sb[t] = (t < SCAN_BLOCKS) ? bsum[t] : 0;
    int i = blockIdx.x * 256 + t;
    int c = (i < N_NODES) ? counts[i * CSTRIDE] : 0;
    ss[t] = c;
    __syncthreads();
    #pragma unroll
    for (int off = 1; off < 256; off <<= 1) {
        int v  = (t >= off) ? ss[t - off] : 0;
        int vb = (t >= off) ? sb[t - off] : 0;
        __syncthreads();
        ss[t] += v;
        sb[t] += vb;
        __syncthreads();
    }
    int base = blockIdx.x ? sb[blockIdx.x - 1] : 0;
    if (i < N_NODES) counts[i * CSTRIDE] = base + ss[t] - c;   // exclusive prefix
}

// Scatter: pos from strided cursor; pre-gather (src,dst) into CSR order so the
// edge kernel's index loads are a single coalesced int2 read (no eidx->ei hop).
__global__ __launch_bounds__(256) void csr_scatter(
    const int* __restrict__ ei, int* __restrict__ cursor,
    int2* __restrict__ sdp, int* __restrict__ eidx)
{
    int e = blockIdx.x * 256 + threadIdx.x;   // grid exact: 800000
    int node = ei[e];
    int pos = atomicAdd(&cursor[node * CSTRIDE], 1);
    sdp[pos] = make_int2(node, ei[N_EDGES + e]);
    eidx[pos] = e;
}

// ---- main (R5-proven structure): per CSR-ordered 64-edge tile: stage z,
// MFMA [64x288]@[288x256], fused act, run-segmented reduction, one atomic per
// distinct (node,col) per tile (~8M vs 102.4M naive).
// NOTE: __launch_bounds__(256,4) — do NOT raise: 4x4 f32x4 acc needs 64 regs;
// (256,6) forces spill (R7: 2.3x regress, scratch traffic 1.6GB). ----
__global__ __launch_bounds__(256, 4) void edge_mfma_scatter(
    const __bf16* __restrict__ hb, const int2* __restrict__ sdp,
    const float* __restrict__ ef, const __bf16* __restrict__ wp,
    const float* __restrict__ gb, const float* __restrict__ cb,
    const int* __restrict__ eidx, float* __restrict__ agg)
{
    __shared__ __align__(16) unsigned char smem[TE * ZSTRIDE * 2]; // 37,888 B
    __shared__ int s_eid[TE], s_src[TE], s_dst[TE];
    __bf16* zs = (__bf16*)smem;
    float*  ms = (float*)smem;       // reused after MFMA (64 x MSTRIDE f32)

    const int t  = threadIdx.x;
    const int e0 = blockIdx.x * TE;

    if (t < TE) {
        int2 p = sdp[e0 + t];        // coalesced 8B — no dependent hop
        s_src[t] = p.x;
        s_dst[t] = p.y;
        s_eid[t] = eidx[e0 + t];
    }
    __syncthreads();

    // ---- stage z tile (bf16): h[src] rows k=0..127, h[dst] k=128..255 ----
    #pragma unroll
    for (int it = 0; it < 8; ++it) {
        int lin = it * 256 + t;
        int region = lin >> 10;            // 0 = src, 1 = dst
        int r   = (lin >> 4) & 63;
        int seg = lin & 15;
        int node = region ? s_dst[r] : s_src[r];
        bf16x8 v = *(const bf16x8*)&hb[(size_t)node * D + seg * 8];
        *(bf16x8*)&zs[r * ZSTRIDE + region * 128 + seg * 8] = v;
    }
    // k 256..287: edge_feat (float2 x5) + zero pad (22)
    if (t < TE) {
        const float* efr = &ef[(size_t)s_eid[t] * DE];   // 40B rows, 8B-aligned
        __bf16* row = &zs[t * ZSTRIDE + 256];
        #pragma unroll
        for (int j = 0; j < 5; ++j) {
            float2 a = *(const float2*)&efr[j * 2];
            bf16x2 p = { (__bf16)a.x, (__bf16)a.y };
            *(bf16x2*)&row[j * 2] = p;
        }
        *(bf16x2*)&row[10] = (bf16x2)(__bf16)0.0f;
        *(bf16x4*)&row[12] = (bf16x4)(__bf16)0.0f;
        *(bf16x8*)&row[16] = (bf16x8)(__bf16)0.0f;
        *(bf16x8*)&row[24] = (bf16x8)(__bf16)0.0f;
    }
    __syncthreads();

    // ---- MFMA: [64 x 288] @ [288 x 256] ----
    const int w     = t >> 6;
    const int l     = t & 63;
    const int quad  = l >> 4;
    const int col16 = l & 15;

    f32x4 acc[4][4];
    #pragma unroll
    for (int mt = 0; mt < 4; ++mt)
        #pragma unroll
        for (int nt = 0; nt < 4; ++nt)
            acc[mt][nt] = (f32x4)0.0f;

    const __bf16* zp  = &zs[col16 * ZSTRIDE + quad * 8];
    const __bf16* wpp = &wp[(size_t)((w * 4) * 64 + l) * 8];

    #pragma unroll
    for (int kb = 0; kb < 9; ++kb) {
        bf16x8 afr[4];
        #pragma unroll
        for (int mt = 0; mt < 4; ++mt)
            afr[mt] = *(const bf16x8*)&zp[mt * 16 * ZSTRIDE + kb * 32];
        bf16x8 bfr[4];
        #pragma unroll
        for (int nt = 0; nt < 4; ++nt)
            bfr[nt] = *(const bf16x8*)&wpp[(size_t)(kb * 16 + nt) * 512];
        #pragma unroll
        for (int mt = 0; mt < 4; ++mt)
            #pragma unroll
            for (int nt = 0; nt < 4; ++nt)
                acc[mt][nt] = __builtin_amdgcn_mfma_f32_16x16x32_bf16(
                    afr[mt], bfr[nt], acc[mt][nt], 0, 0, 0);
    }
    __syncthreads();   // all waves done reading zs; safe to overwrite as ms

    // ---- m = sigmoid(g+gb)*softplus(c+cb) -> LDS ----
    const int colA = w * 32 + col16;
    const int colB = colA + 16;
    const float gbA = gb[colA], cbA = cb[colA];
    const float gbB = gb[colB], cbB = cb[colB];

    #pragma unroll
    for (int mt = 0; mt < 4; ++mt) {
        #pragma unroll
        for (int r = 0; r < 4; ++r) {
            int e = mt * 16 + quad * 4 + r;
            ms[e * MSTRIDE + colA] =
                fast_sigmoid(acc[mt][0][r] + gbA) * fast_softplus(acc[mt][1][r] + cbA);
            ms[e * MSTRIDE + colB] =
                fast_sigmoid(acc[mt][2][r] + gbB) * fast_softplus(acc[mt][3][r] + cbB);
        }
    }
    __syncthreads();

    // ---- run-segmented reduction over CSR-sorted rows, one atomic per run ----
    const int half = t >> 7;           // rows [half*32, half*32+32)
    const int c    = t & 127;
    const int rlo  = half * 32, rhi = rlo + 32;
    int   cur = s_src[rlo];
    float s   = 0.0f;
    for (int e = rlo; e < rhi; ++e) {
        int node = s_src[e];
        float v  = ms[e * MSTRIDE + c];
        if (node != cur) {
            atomicAdd(&agg[(size_t)cur * D + c], s);
            s = 0.0f; cur = node;
        }
        s += v;
    }
    atomicAdd(&agg[(size_t)cur * D + c], s);
}

__global__ __launch_bounds__(256) void col_stats(
    const float* __restrict__ agg, float* __restrict__ stats)
{
    const int t    = threadIdx.x;
    const int col  = t & 127;
    const int half = t >> 7;
    float s = 0.0f, s2 = 0.0f;
    for (int r = blockIdx.x * 2 + half; r < N_NODES; r += gridDim.x * 2) {
        float v = agg[(size_t)r * D + col];
        s += v; s2 += v * v;
    }
    atomicAdd(&stats[col], s);
    atomicAdd(&stats[128 + col], s2);
}

// BN finalize folded in: each block recomputes scale/bias from L2-hot stats.
__global__ __launch_bounds__(256) void out_softplus(
    const float* __restrict__ h, const float* __restrict__ agg,
    const float* __restrict__ stats, const float* __restrict__ gamma,
    const float* __restrict__ beta, float* __restrict__ out)
{
    __shared__ float sc[128], bi[128];
    int t = threadIdx.x;
    if (t < 128) {
        const float inv_n = 1.0f / (float)N_NODES;
        float mean = stats[t] * inv_n;
        float var  = stats[128 + t] * inv_n - mean * mean;
        var = fmaxf(var, 0.0f);
        float rstd = rsqrtf(var + 1e-5f);
        float s = rstd * gamma[t];
        sc[t] = s;
        bi[t] = beta[t] - mean * s;
    }
    __syncthreads();
    int idx4 = blockIdx.x * 256 + t;
    int base = idx4 * 4;
    if (base < N_NODES * D) {
        float4 hv = *(const float4*)&h[base];
        float4 av = *(const float4*)&agg[base];
        int c = base & 127;
        float4 o;
        o.x = fast_softplus(hv.x + av.x * sc[c + 0] + bi[c + 0]);
        o.y = fast_softplus(hv.y + av.y * sc[c + 1] + bi[c + 1]);
        o.z = fast_softplus(hv.z + av.z * sc[c + 2] + bi[c + 2]);
        o.w = fast_softplus(hv.w + av.w * sc[c + 3] + bi[c + 3]);
        *(float4*)&out[base] = o;
    }
}

extern "C" void kernel_launch(void* const* d_in, const int* in_sizes, int n_in,
                              void* d_out, int out_size, void* d_ws, size_t ws_size,
                              hipStream_t stream) {
    const float* h     = (const float*)d_in[0];
    const int*   ei    = (const int*)  d_in[1];
    const float* ef    = (const float*)d_in[2];
    const float* gw    = (const float*)d_in[3];
    const float* gb    = (const float*)d_in[4];
    const float* cw    = (const float*)d_in[5];
    const float* cb    = (const float*)d_in[6];
    const float* gamma = (const float*)d_in[7];
    const float* beta  = (const float*)d_in[8];
    float* out = (float*)d_out;

    // zeroed region first (one memset): agg | stats | counts(strided)
    float*  agg     = (float*)d_ws;                       // 25.6 MB
    float*  stats   = agg + (size_t)N_NODES * D;          // 256 f
    int*    counts  = (int*)(stats + 256);                // 3.2 MB (node*16; cursor reuses)
    int*    bsum    = counts + N_NODES * CSTRIDE;         // 256 ints
    __bf16* wp      = (__bf16*)(bsum + 256);              // 144 KB (16B-aligned)
    __bf16* hb      = wp + WP_ELEMS;                      // 12.8 MB (16B-aligned)
    int2*   sdp     = (int2*)(hb + (size_t)N_NODES * D);  // 6.4 MB (8B-aligned)
    int*    eidx    = (int*)(sdp + N_EDGES);              // 3.2 MB
    // total ~51.4 MB (< 58.6 MB proven in R2)

    const size_t zero_bytes = ((size_t)N_NODES * D + 256) * sizeof(float)
                            + (size_t)N_NODES * CSTRIDE * sizeof(int);
    hipMemsetAsync(d_ws, 0, zero_bytes, stream);
    prep<<<9663, 256, 0, stream>>>(h, gw, cw, ei, hb, wp, counts);
    scan_partials<<<SCAN_BLOCKS, 256, 0, stream>>>(counts, bsum);
    scan_final<<<SCAN_BLOCKS, 256, 0, stream>>>(counts, bsum);
    csr_scatter<<<N_EDGES / 256, 256, 0, stream>>>(ei, counts, sdp, eidx);
    edge_mfma_scatter<<<N_TILES, 256, 0, stream>>>(hb, sdp, ef, wp, gb, cb, eidx, agg);
    col_stats<<<784, 256, 0, stream>>>(agg, stats);
    out_softplus<<<(N_NODES * D / 4 + 255) / 256, 256, 0, stream>>>(
        h, agg, stats, gamma, beta, out);
}